// Round 14
// baseline (386.840 us; speedup 1.0000x reference)
//
#include <hip/hip_runtime.h>

#define K_FEATS 256
#define C_FEATS 64
#define RCHUNK 1024
#define RROUNDS (RCHUNK / 64)
#define NDIGIT 512           // digit = dst>>7, dst<65536 -> digit<512
#define DSHIFT 7
#define NMASK 127

typedef __attribute__((ext_vector_type(8))) short short8;
typedef __attribute__((ext_vector_type(8))) unsigned short ushort8;
typedef __attribute__((ext_vector_type(4))) float f32x4;

__device__ __forceinline__ unsigned short f2bf(float f) {
    union { float f; unsigned u; } v; v.f = f;
    unsigned r = v.u + 0x7FFF + ((v.u >> 16) & 1);   // RNE, finite inputs
    return (unsigned short)(r >> 16);
}

__device__ __forceinline__ float bflo(unsigned u) { return __uint_as_float(u << 16); }
__device__ __forceinline__ float bfhi(unsigned u) { return __uint_as_float(u & 0xFFFF0000u); }

// ---------------------------------------------------------------------------
// ws layout (bytes) — every GLOBAL buffer is a pure function of the inputs.
// nchunk = 782.
//   P1 (uint)   : 0          ..  3,200,000   (dst&127)<<16|src, sorted by dst>>7
//   dm (int)    : 3,200,000  ..  4,801,536   [digit][chunk] within-bucket offsets
//   cm16 (u16)  : 4,801,536  ..  5,602,304   [chunk][512 digits] coalesced
//   hwn (bf16)  : 5,602,304  .. 12,002,304
//   totals(int) : 12,002,304 .. 12,004,352   per-digit bucket sizes
//   wt_g (bf16) : 12,004,352 .. 12,037,120   W^T bf16 (16B aligned)
// total ~12.04 MB
// ---------------------------------------------------------------------------

// fused: per-chunk 512-bin digit histogram (u16 chunk-major, coalesced)
// [blocks 0..nchunk) + W transpose to bf16 [blocks nchunk..nchunk+16)
__global__ __launch_bounds__(256) void packhist_w_kernel(
    const int* __restrict__ dst, unsigned short* __restrict__ cm16,
    const float* __restrict__ w, unsigned short* __restrict__ wt,
    int n_edges, int nchunk)
{
    const int tid = threadIdx.x;
    if ((int)blockIdx.x < nchunk) {
        __shared__ unsigned cnt[NDIGIT];
        #pragma unroll
        for (int j = 0; j < NDIGIT / 256; ++j) cnt[tid + j * 256] = 0;
        __syncthreads();
        const int e0 = blockIdx.x * RCHUNK + tid * 4;
        if (e0 + 3 < n_edges) {
            const int4 d4 = *reinterpret_cast<const int4*>(dst + e0);
            atomicAdd(&cnt[d4.x >> DSHIFT], 1);
            atomicAdd(&cnt[d4.y >> DSHIFT], 1);
            atomicAdd(&cnt[d4.z >> DSHIFT], 1);
            atomicAdd(&cnt[d4.w >> DSHIFT], 1);
        } else {
            #pragma unroll
            for (int j = 0; j < 4; ++j) {
                if (e0 + j < n_edges) atomicAdd(&cnt[dst[e0 + j] >> DSHIFT], 1);
            }
        }
        __syncthreads();
        const unsigned o = cnt[tid * 2] | (cnt[tid * 2 + 1] << 16);
        reinterpret_cast<unsigned*>(cm16)[(size_t)blockIdx.x * (NDIGIT / 2) + tid] = o;
    } else {
        const int e2 = ((int)blockIdx.x - nchunk) * 1024 + tid;
        #pragma unroll
        for (int j = 0; j < 4; ++j) {
            const int idx = e2 + j * 256;           // linear in wt [col][k]
            const int col = idx >> 8, k = idx & 255;
            wt[idx] = f2bf(w[k * C_FEATS + col]);
        }
    }
}

// one block per digit: exclusive scan of its 782 chunk counts (-> dm row,
// within-bucket offsets) + bucket total. Thread t owns chunks 4t..4t+3.
__global__ __launch_bounds__(256) void bucketscan_kernel(
    const unsigned short* __restrict__ cm16, int* __restrict__ dm,
    int* __restrict__ totals, int nchunk)
{
    __shared__ int s[256];
    const int g = blockIdx.x;
    const int t = threadIdx.x;
    int v[4];
    int sum = 0;
    #pragma unroll
    for (int j = 0; j < 4; ++j) {
        const int c = t * 4 + j;
        v[j] = (c < nchunk) ? (int)cm16[(size_t)c * NDIGIT + g] : 0;
        sum += v[j];
    }
    s[t] = sum;
    __syncthreads();
    #pragma unroll
    for (int d = 1; d < 256; d <<= 1) {
        int x = (t >= d) ? s[t - d] : 0;
        __syncthreads();
        s[t] += x;
        __syncthreads();
    }
    int base = s[t] - sum;
    #pragma unroll
    for (int j = 0; j < 4; ++j) {
        const int c = t * 4 + j;
        if (c < nchunk) dm[(size_t)g * nchunk + c] = base;
        base += v[j];
    }
    if (t == 255) totals[g] = s[255];
}

// ---------------------------------------------------------------------------
// FUSED: blocks [0,nreb) = deterministic stable radix scatter (4 waves/block,
// one 1024-edge chunk per wave, wave-private LDS cnt); blocks [nreb,..) =
// MFMA projection. Reorder blocks first redundantly scan totals -> digbaseL.
// (validated round 13)
// ---------------------------------------------------------------------------
__global__ __launch_bounds__(256) void reorder_gemm_kernel(
    const int* __restrict__ src, const int* __restrict__ dst,
    unsigned* __restrict__ P1, const int* __restrict__ dm,
    const int* __restrict__ totals,
    const float* __restrict__ h, const unsigned short* __restrict__ wt_g,
    const float* __restrict__ norm, unsigned short* __restrict__ hwn,
    int n_edges, int nchunk, int n_nodes, int nreb)
{
    __shared__ __align__(16) unsigned char lds[65536];
    const int tid = threadIdx.x;

    if ((int)blockIdx.x < nreb) {
        unsigned* cntall  = reinterpret_cast<unsigned*>(lds);        // 4*512*4 = 8KB
        int* ss           = reinterpret_cast<int*>(lds + 8192);      // 1KB
        int* digbaseL     = reinterpret_cast<int*>(lds + 9216);      // 2KB
        // exclusive scan of totals (512 entries, 2 per thread)
        {
            const int a  = totals[2 * tid];
            const int b2 = totals[2 * tid + 1];
            ss[tid] = a + b2;
            __syncthreads();
            #pragma unroll
            for (int d = 1; d < 256; d <<= 1) {
                int x = (tid >= d) ? ss[tid - d] : 0;
                __syncthreads();
                ss[tid] += x;
                __syncthreads();
            }
            const int base = ss[tid] - (a + b2);
            digbaseL[2 * tid]     = base;
            digbaseL[2 * tid + 1] = base + a;
            __syncthreads();
        }
        const int wv = tid >> 6;
        const int c = blockIdx.x * 4 + wv;
        if (c >= nchunk) return;
        unsigned* cnt = cntall + wv * NDIGIT;
        const int lane = tid & 63;
        #pragma unroll
        for (int j = 0; j < NDIGIT / 64; ++j) cnt[lane + j * 64] = 0;
        // no barrier: cnt is wave-private; LDS ops are wave-ordered
        const int base = c * RCHUNK;

        unsigned dA = 0, sA = 0, dB = 0, sB = 0;
        if (base + lane < n_edges)      { dA = dst[base + lane];      sA = src[base + lane]; }
        if (base + 64 + lane < n_edges) { dB = dst[base + 64 + lane]; sB = src[base + 64 + lane]; }

        for (int r = 0; r < RROUNDS; ++r) {
            unsigned dC = 0, sC = 0;
            const int idxC = base + (r + 2) * 64 + lane;
            if (r + 2 < RROUNDS && idxC < n_edges) { dC = dst[idxC]; sC = src[idxC]; }

            const int idx = base + r * 64 + lane;
            const bool valid = idx < n_edges;
            const int g = valid ? (int)(dA >> DSHIFT) : NDIGIT;
            unsigned long long m = ~0ull;
            #pragma unroll
            for (int b = 0; b < 10; ++b) {
                const unsigned long long bb = __ballot((g >> b) & 1);
                m &= ((g >> b) & 1) ? bb : ~bb;
            }
            const unsigned long long below = m & ((1ull << lane) - 1ull);
            const int laneRank = __popcll(below);
            const int total = __popcll(m);
            const bool isFirst = (below == 0ull);
            if (valid) {
                const unsigned oldc = cnt[g];
                const unsigned slot = (unsigned)digbaseL[g]
                                    + (unsigned)dm[(size_t)g * nchunk + c]
                                    + oldc + (unsigned)laneRank;
                P1[slot] = ((dA & (unsigned)NMASK) << 16) | sA;
                if (isFirst) cnt[g] = oldc + (unsigned)total;
            }
            dA = dB; sA = sB; dB = dC; sB = sC;
        }
    } else {
        // ---- gemm (validated) ----
        const int row0 = ((int)blockIdx.x - nreb) * 64;

        #pragma unroll
        for (int j = 0; j < 8; ++j) {
            const int ch = j * 256 + tid;
            const int r = ch >> 5, k0 = (ch & 31) * 8;
            const int row = row0 + r;
            ushort8 v;
            if (row < n_nodes) {
                const float4 f0 = *reinterpret_cast<const float4*>(h + (size_t)row * K_FEATS + k0);
                const float4 f1 = *reinterpret_cast<const float4*>(h + (size_t)row * K_FEATS + k0 + 4);
                v[0]=f2bf(f0.x); v[1]=f2bf(f0.y); v[2]=f2bf(f0.z); v[3]=f2bf(f0.w);
                v[4]=f2bf(f1.x); v[5]=f2bf(f1.y); v[6]=f2bf(f1.z); v[7]=f2bf(f1.w);
            } else {
                v = (ushort8)0;
            }
            const int addr = (r * 512 + k0 * 2) ^ ((r & 7) << 4);
            *reinterpret_cast<ushort8*>(lds + addr) = v;
        }
        #pragma unroll
        for (int j = 0; j < 8; ++j) {
            const int ch = j * 256 + tid;
            const int col = ch >> 5, k0 = (ch & 31) * 8;
            const ushort8 v = *reinterpret_cast<const ushort8*>(wt_g + ch * 8);
            const int addr = 32768 + ((col * 512 + k0 * 2) ^ ((col & 7) << 4));
            *reinterpret_cast<ushort8*>(lds + addr) = v;
        }
        __syncthreads();

        const int lane = tid & 63, w = tid >> 6;
        const int r16 = lane & 15, kg = lane >> 4;
        const int x = (r16 & 7) << 4;

        f32x4 acc[4];
        #pragma unroll
        for (int n = 0; n < 4; ++n) acc[n] = (f32x4)0.f;

        #pragma unroll
        for (int kb = 0; kb < 8; ++kb) {
            const int common = (r16 * 512 + kb * 64 + kg * 16) ^ x;
            const short8 a = *reinterpret_cast<const short8*>(lds + w * 8192 + common);
            #pragma unroll
            for (int n = 0; n < 4; ++n) {
                const short8 b = *reinterpret_cast<const short8*>(lds + 32768 + n * 8192 + common);
                acc[n] = __builtin_amdgcn_mfma_f32_16x16x32_bf16(a, b, acc[n], 0, 0, 0);
            }
        }

        #pragma unroll
        for (int i = 0; i < 4; ++i) {
            const int row = row0 + w * 16 + kg * 4 + i;
            if (row < n_nodes) {
                const float nv = norm[row];
                #pragma unroll
                for (int n = 0; n < 4; ++n) {
                    hwn[(size_t)row * C_FEATS + n * 16 + r16] = f2bf(acc[n][i] * nv);
                }
            }
        }
    }
}

// ---------------------------------------------------------------------------
// Aggregate + finalize via direct LDS f32 accumulation. Block = 128-node
// bucket, 512 threads. acc[node][feat] padded to stride 65 (bank =
// (node+feat)&31 -> ~2-way, free). Stream edges in P1 order: 8 edges/wave/
// iter, unroll 2 (16 gathers in flight); 8 ds_add_f32 per lane hide under
// L3 gather latency. No staging, no per-node split, no shfl reduce, no
// capacity limit. LDS-atomic order only perturbs f32 rounding (~1e-6).
// ---------------------------------------------------------------------------
__global__ __launch_bounds__(512) void aggregate_kernel(
    const uint4* __restrict__ hwn4, const unsigned* __restrict__ P1,
    const int* __restrict__ totals,
    const float* __restrict__ norm, const float* __restrict__ bias,
    float* __restrict__ out, int n_nodes, int n_edges)
{
    __shared__ int ds[NDIGIT];
    __shared__ float acc[128 * 65];

    const int tid = threadIdx.x;
    const int b = blockIdx.x;
    const int n0 = b * 128;

    for (int i = tid; i < 128 * 65; i += 512) acc[i] = 0.f;

    // exclusive scan of totals (512 entries, 1 per thread)
    const int v = totals[tid];
    ds[tid] = v;
    __syncthreads();
    #pragma unroll
    for (int d = 1; d < NDIGIT; d <<= 1) {
        int x = (tid >= d) ? ds[tid - d] : 0;
        __syncthreads();
        ds[tid] += x;
        __syncthreads();
    }
    const int incl = ds[tid];
    __syncthreads();
    ds[tid] = incl - v;     // exclusive
    __syncthreads();

    const int s = ds[b];
    const int bucketsz = ((b + 1 < NDIGIT) ? ds[b + 1] : n_edges) - s;

    const int lane = tid & 63;
    const int wv = tid >> 6;           // 8 waves
    const int q  = lane >> 3;          // edge slot 0..7
    const int c8 = lane & 7;           // uint4 index within 128B row

    int e = wv * 8 + q;
    for (; e + 64 < bucketsz; e += 128) {
        const unsigned k0 = P1[s + e];
        const unsigned k1 = P1[s + e + 64];
        const uint4 u  = hwn4[(size_t)(k0 & 0xFFFFu) * 8 + c8];
        const uint4 w2 = hwn4[(size_t)(k1 & 0xFFFFu) * 8 + c8];
        float* a0 = &acc[(k0 >> 16) * 65 + c8 * 8];
        atomicAdd(a0 + 0, bflo(u.x)); atomicAdd(a0 + 1, bfhi(u.x));
        atomicAdd(a0 + 2, bflo(u.y)); atomicAdd(a0 + 3, bfhi(u.y));
        atomicAdd(a0 + 4, bflo(u.z)); atomicAdd(a0 + 5, bfhi(u.z));
        atomicAdd(a0 + 6, bflo(u.w)); atomicAdd(a0 + 7, bfhi(u.w));
        float* a1 = &acc[(k1 >> 16) * 65 + c8 * 8];
        atomicAdd(a1 + 0, bflo(w2.x)); atomicAdd(a1 + 1, bfhi(w2.x));
        atomicAdd(a1 + 2, bflo(w2.y)); atomicAdd(a1 + 3, bfhi(w2.y));
        atomicAdd(a1 + 4, bflo(w2.z)); atomicAdd(a1 + 5, bfhi(w2.z));
        atomicAdd(a1 + 6, bflo(w2.w)); atomicAdd(a1 + 7, bfhi(w2.w));
    }
    for (; e < bucketsz; e += 64) {
        const unsigned k0 = P1[s + e];
        const uint4 u = hwn4[(size_t)(k0 & 0xFFFFu) * 8 + c8];
        float* a0 = &acc[(k0 >> 16) * 65 + c8 * 8];
        atomicAdd(a0 + 0, bflo(u.x)); atomicAdd(a0 + 1, bfhi(u.x));
        atomicAdd(a0 + 2, bflo(u.y)); atomicAdd(a0 + 3, bfhi(u.y));
        atomicAdd(a0 + 4, bflo(u.z)); atomicAdd(a0 + 5, bfhi(u.z));
        atomicAdd(a0 + 6, bflo(u.w)); atomicAdd(a0 + 7, bfhi(u.w));
    }
    __syncthreads();

    // finalize: thread -> (node = tid>>2, feats (tid&3)*16 .. +16)
    const int nn = tid >> 2;
    const int node = n0 + nn;
    if (node < n_nodes) {
        const int f0 = (tid & 3) * 16;
        const float nv = norm[node];
        const float* ap = &acc[nn * 65 + f0];
        float* po = out + (size_t)node * C_FEATS + f0;
        #pragma unroll
        for (int j4 = 0; j4 < 4; ++j4) {
            const float4 bv = *reinterpret_cast<const float4*>(bias + f0 + j4 * 4);
            float4 o;
            o.x = fmaxf(fmaf(ap[j4 * 4 + 0], nv, bv.x), 0.f);
            o.y = fmaxf(fmaf(ap[j4 * 4 + 1], nv, bv.y), 0.f);
            o.z = fmaxf(fmaf(ap[j4 * 4 + 2], nv, bv.z), 0.f);
            o.w = fmaxf(fmaf(ap[j4 * 4 + 3], nv, bv.w), 0.f);
            *reinterpret_cast<float4*>(po + j4 * 4) = o;
        }
    }
}

extern "C" void kernel_launch(void* const* d_in, const int* in_sizes, int n_in,
                              void* d_out, int out_size, void* d_ws, size_t ws_size,
                              hipStream_t stream) {
    const float* h      = (const float*)d_in[0];
    const float* norm   = (const float*)d_in[1];
    const int*   src    = (const int*)d_in[2];
    const int*   dst    = (const int*)d_in[3];
    const float* weight = (const float*)d_in[4];
    const float* bias   = (const float*)d_in[5];

    const int n_nodes = in_sizes[1];
    const int n_edges = in_sizes[2];

    char* ws = (char*)d_ws;
    unsigned* P1            = (unsigned*)(ws + 0);
    int* dm                 = (int*)(ws + 3200000);
    unsigned short* cm16    = (unsigned short*)(ws + 4801536);
    unsigned short* hwn     = (unsigned short*)(ws + 5602304);
    int* totals             = (int*)(ws + 12002304);
    unsigned short* wt_g    = (unsigned short*)(ws + 12004352);

    const int nchunk  = (n_edges + RCHUNK - 1) / RCHUNK;          // 782
    const int ngroup  = (n_nodes + 127) / 128;                    // 391
    const int nreb    = (nchunk + 3) / 4;                         // 196
    const int ngemm   = (n_nodes + 63) / 64;                      // 782

    // 1) fused digit histogram (u16 chunk-major) + W transpose
    packhist_w_kernel<<<nchunk + 16, 256, 0, stream>>>(dst, cm16, weight, wt_g,
                                                       n_edges, nchunk);
    // 2) per-bucket scan of chunk counts -> dm (within-bucket) + totals
    bucketscan_kernel<<<NDIGIT, 256, 0, stream>>>(cm16, dm, totals, nchunk);
    // 3) FUSED reorder (196 blocks) + gemm (782 blocks) — concurrent
    reorder_gemm_kernel<<<nreb + ngemm, 256, 0, stream>>>(
        src, dst, P1, dm, totals, h, wt_g, norm, hwn,
        n_edges, nchunk, n_nodes, nreb);
    // 4) LDS-accumulate aggregate + finalize
    aggregate_kernel<<<ngroup, 512, 0, stream>>>(
        (const uint4*)hwn, P1, totals, norm, bias, (float*)d_out, n_nodes, n_edges);
}

// Round 15
// 70.756 us; speedup vs baseline: 5.4673x; 5.4673x over previous
//
#include <hip/hip_runtime.h>

#define K_FEATS 256
#define C_FEATS 64
#define RCHUNK 1024
#define RROUNDS (RCHUNK / 64)
#define NDIGIT 512           // digit = dst>>7, dst<65536 -> digit<512
#define DSHIFT 7
#define NMASK 127
#define LCAP 2560            // per-bucket LDS edge capacity (avg 2048)

typedef __attribute__((ext_vector_type(8))) short short8;
typedef __attribute__((ext_vector_type(8))) unsigned short ushort8;
typedef __attribute__((ext_vector_type(4))) float f32x4;

__device__ __forceinline__ unsigned short f2bf(float f) {
    union { float f; unsigned u; } v; v.f = f;
    unsigned r = v.u + 0x7FFF + ((v.u >> 16) & 1);   // RNE, finite inputs
    return (unsigned short)(r >> 16);
}

__device__ __forceinline__ float bflo(unsigned u) { return __uint_as_float(u << 16); }
__device__ __forceinline__ float bfhi(unsigned u) { return __uint_as_float(u & 0xFFFF0000u); }

// ---------------------------------------------------------------------------
// ws layout (bytes) — every GLOBAL buffer is a pure function of the inputs.
// nchunk = 782.
//   P1 (uint)   : 0          ..  3,200,000   (dst&127)<<16|src, sorted by dst>>7
//   dm (int)    : 3,200,000  ..  4,801,536   [digit][chunk] within-bucket offsets
//   cm16 (u16)  : 4,801,536  ..  5,602,304   [chunk][512 digits] coalesced
//   hwn (bf16)  : 5,602,304  .. 12,002,304
//   totals(int) : 12,002,304 .. 12,004,352   per-digit bucket sizes
//   wt_g (bf16) : 12,004,352 .. 12,037,120   W^T bf16 (16B aligned)
// total ~12.04 MB
// ---------------------------------------------------------------------------

// fused: per-chunk 512-bin digit histogram (u16 chunk-major, coalesced)
// [blocks 0..nchunk) + W transpose to bf16 [blocks nchunk..nchunk+16)
__global__ __launch_bounds__(256) void packhist_w_kernel(
    const int* __restrict__ dst, unsigned short* __restrict__ cm16,
    const float* __restrict__ w, unsigned short* __restrict__ wt,
    int n_edges, int nchunk)
{
    const int tid = threadIdx.x;
    if ((int)blockIdx.x < nchunk) {
        __shared__ unsigned cnt[NDIGIT];
        #pragma unroll
        for (int j = 0; j < NDIGIT / 256; ++j) cnt[tid + j * 256] = 0;
        __syncthreads();
        const int e0 = blockIdx.x * RCHUNK + tid * 4;
        if (e0 + 3 < n_edges) {
            const int4 d4 = *reinterpret_cast<const int4*>(dst + e0);
            atomicAdd(&cnt[d4.x >> DSHIFT], 1);
            atomicAdd(&cnt[d4.y >> DSHIFT], 1);
            atomicAdd(&cnt[d4.z >> DSHIFT], 1);
            atomicAdd(&cnt[d4.w >> DSHIFT], 1);
        } else {
            #pragma unroll
            for (int j = 0; j < 4; ++j) {
                if (e0 + j < n_edges) atomicAdd(&cnt[dst[e0 + j] >> DSHIFT], 1);
            }
        }
        __syncthreads();
        const unsigned o = cnt[tid * 2] | (cnt[tid * 2 + 1] << 16);
        reinterpret_cast<unsigned*>(cm16)[(size_t)blockIdx.x * (NDIGIT / 2) + tid] = o;
    } else {
        const int e2 = ((int)blockIdx.x - nchunk) * 1024 + tid;
        #pragma unroll
        for (int j = 0; j < 4; ++j) {
            const int idx = e2 + j * 256;           // linear in wt [col][k]
            const int col = idx >> 8, k = idx & 255;
            wt[idx] = f2bf(w[k * C_FEATS + col]);
        }
    }
}

// one block per digit: exclusive scan of its 782 chunk counts (-> dm row,
// within-bucket offsets) + bucket total. Thread t owns chunks 4t..4t+3.
__global__ __launch_bounds__(256) void bucketscan_kernel(
    const unsigned short* __restrict__ cm16, int* __restrict__ dm,
    int* __restrict__ totals, int nchunk)
{
    __shared__ int s[256];
    const int g = blockIdx.x;
    const int t = threadIdx.x;
    int v[4];
    int sum = 0;
    #pragma unroll
    for (int j = 0; j < 4; ++j) {
        const int c = t * 4 + j;
        v[j] = (c < nchunk) ? (int)cm16[(size_t)c * NDIGIT + g] : 0;
        sum += v[j];
    }
    s[t] = sum;
    __syncthreads();
    #pragma unroll
    for (int d = 1; d < 256; d <<= 1) {
        int x = (t >= d) ? s[t - d] : 0;
        __syncthreads();
        s[t] += x;
        __syncthreads();
    }
    int base = s[t] - sum;
    #pragma unroll
    for (int j = 0; j < 4; ++j) {
        const int c = t * 4 + j;
        if (c < nchunk) dm[(size_t)g * nchunk + c] = base;
        base += v[j];
    }
    if (t == 255) totals[g] = s[255];
}

// ---------------------------------------------------------------------------
// FUSED: blocks [0,nreb) = deterministic stable radix scatter (4 waves/block,
// one 1024-edge chunk per wave, wave-private LDS cnt); blocks [nreb,..) =
// MFMA projection. Reorder blocks first redundantly scan totals -> digbaseL.
// (validated round 13)
// ---------------------------------------------------------------------------
__global__ __launch_bounds__(256) void reorder_gemm_kernel(
    const int* __restrict__ src, const int* __restrict__ dst,
    unsigned* __restrict__ P1, const int* __restrict__ dm,
    const int* __restrict__ totals,
    const float* __restrict__ h, const unsigned short* __restrict__ wt_g,
    const float* __restrict__ norm, unsigned short* __restrict__ hwn,
    int n_edges, int nchunk, int n_nodes, int nreb)
{
    __shared__ __align__(16) unsigned char lds[65536];
    const int tid = threadIdx.x;

    if ((int)blockIdx.x < nreb) {
        unsigned* cntall  = reinterpret_cast<unsigned*>(lds);        // 4*512*4 = 8KB
        int* ss           = reinterpret_cast<int*>(lds + 8192);      // 1KB
        int* digbaseL     = reinterpret_cast<int*>(lds + 9216);      // 2KB
        // exclusive scan of totals (512 entries, 2 per thread)
        {
            const int a  = totals[2 * tid];
            const int b2 = totals[2 * tid + 1];
            ss[tid] = a + b2;
            __syncthreads();
            #pragma unroll
            for (int d = 1; d < 256; d <<= 1) {
                int x = (tid >= d) ? ss[tid - d] : 0;
                __syncthreads();
                ss[tid] += x;
                __syncthreads();
            }
            const int base = ss[tid] - (a + b2);
            digbaseL[2 * tid]     = base;
            digbaseL[2 * tid + 1] = base + a;
            __syncthreads();
        }
        const int wv = tid >> 6;
        const int c = blockIdx.x * 4 + wv;
        if (c >= nchunk) return;
        unsigned* cnt = cntall + wv * NDIGIT;
        const int lane = tid & 63;
        #pragma unroll
        for (int j = 0; j < NDIGIT / 64; ++j) cnt[lane + j * 64] = 0;
        // no barrier: cnt is wave-private; LDS ops are wave-ordered
        const int base = c * RCHUNK;

        unsigned dA = 0, sA = 0, dB = 0, sB = 0;
        if (base + lane < n_edges)      { dA = dst[base + lane];      sA = src[base + lane]; }
        if (base + 64 + lane < n_edges) { dB = dst[base + 64 + lane]; sB = src[base + 64 + lane]; }

        for (int r = 0; r < RROUNDS; ++r) {
            unsigned dC = 0, sC = 0;
            const int idxC = base + (r + 2) * 64 + lane;
            if (r + 2 < RROUNDS && idxC < n_edges) { dC = dst[idxC]; sC = src[idxC]; }

            const int idx = base + r * 64 + lane;
            const bool valid = idx < n_edges;
            const int g = valid ? (int)(dA >> DSHIFT) : NDIGIT;
            unsigned long long m = ~0ull;
            #pragma unroll
            for (int b = 0; b < 10; ++b) {
                const unsigned long long bb = __ballot((g >> b) & 1);
                m &= ((g >> b) & 1) ? bb : ~bb;
            }
            const unsigned long long below = m & ((1ull << lane) - 1ull);
            const int laneRank = __popcll(below);
            const int total = __popcll(m);
            const bool isFirst = (below == 0ull);
            if (valid) {
                const unsigned oldc = cnt[g];
                const unsigned slot = (unsigned)digbaseL[g]
                                    + (unsigned)dm[(size_t)g * nchunk + c]
                                    + oldc + (unsigned)laneRank;
                P1[slot] = ((dA & (unsigned)NMASK) << 16) | sA;
                if (isFirst) cnt[g] = oldc + (unsigned)total;
            }
            dA = dB; sA = sB; dB = dC; sB = sC;
        }
    } else {
        // ---- gemm (validated) ----
        const int row0 = ((int)blockIdx.x - nreb) * 64;

        #pragma unroll
        for (int j = 0; j < 8; ++j) {
            const int ch = j * 256 + tid;
            const int r = ch >> 5, k0 = (ch & 31) * 8;
            const int row = row0 + r;
            ushort8 v;
            if (row < n_nodes) {
                const float4 f0 = *reinterpret_cast<const float4*>(h + (size_t)row * K_FEATS + k0);
                const float4 f1 = *reinterpret_cast<const float4*>(h + (size_t)row * K_FEATS + k0 + 4);
                v[0]=f2bf(f0.x); v[1]=f2bf(f0.y); v[2]=f2bf(f0.z); v[3]=f2bf(f0.w);
                v[4]=f2bf(f1.x); v[5]=f2bf(f1.y); v[6]=f2bf(f1.z); v[7]=f2bf(f1.w);
            } else {
                v = (ushort8)0;
            }
            const int addr = (r * 512 + k0 * 2) ^ ((r & 7) << 4);
            *reinterpret_cast<ushort8*>(lds + addr) = v;
        }
        #pragma unroll
        for (int j = 0; j < 8; ++j) {
            const int ch = j * 256 + tid;
            const int col = ch >> 5, k0 = (ch & 31) * 8;
            const ushort8 v = *reinterpret_cast<const ushort8*>(wt_g + ch * 8);
            const int addr = 32768 + ((col * 512 + k0 * 2) ^ ((col & 7) << 4));
            *reinterpret_cast<ushort8*>(lds + addr) = v;
        }
        __syncthreads();

        const int lane = tid & 63, w = tid >> 6;
        const int r16 = lane & 15, kg = lane >> 4;
        const int x = (r16 & 7) << 4;

        f32x4 acc[4];
        #pragma unroll
        for (int n = 0; n < 4; ++n) acc[n] = (f32x4)0.f;

        #pragma unroll
        for (int kb = 0; kb < 8; ++kb) {
            const int common = (r16 * 512 + kb * 64 + kg * 16) ^ x;
            const short8 a = *reinterpret_cast<const short8*>(lds + w * 8192 + common);
            #pragma unroll
            for (int n = 0; n < 4; ++n) {
                const short8 b = *reinterpret_cast<const short8*>(lds + 32768 + n * 8192 + common);
                acc[n] = __builtin_amdgcn_mfma_f32_16x16x32_bf16(a, b, acc[n], 0, 0, 0);
            }
        }

        #pragma unroll
        for (int i = 0; i < 4; ++i) {
            const int row = row0 + w * 16 + kg * 4 + i;
            if (row < n_nodes) {
                const float nv = norm[row];
                #pragma unroll
                for (int n = 0; n < 4; ++n) {
                    hwn[(size_t)row * C_FEATS + n * 16 + r16] = f2bf(acc[n][i] * nv);
                }
            }
        }
    }
}

// ---------------------------------------------------------------------------
// Aggregate + finalize (validated round 13). Block = 128-node bucket,
// 512 threads. Bucket bounds via redundant LDS scan of totals; per-node
// segments via count (1 atomic/edge) -> shfl scan -> cursor scatter; then
// 8-edge-parallel uint4 gather + shfl_xor reduce; fused norm/bias/relu.
// ---------------------------------------------------------------------------
__global__ __launch_bounds__(512) void aggregate_kernel(
    const uint4* __restrict__ hwn4, const unsigned* __restrict__ P1,
    const int* __restrict__ totals,
    const float* __restrict__ norm, const float* __restrict__ bias,
    float* __restrict__ out, int n_nodes, int n_edges)
{
    __shared__ unsigned stage[LCAP];
    __shared__ unsigned short lsrc[LCAP];
    __shared__ int cnt128[128];
    __shared__ int cur128[128];
    __shared__ int segbase[129];
    __shared__ int ds[NDIGIT];

    const int tid = threadIdx.x;
    const int b = blockIdx.x;
    const int n0 = b * 128;

    // exclusive scan of totals (512 entries, 1 per thread)
    const int v = totals[tid];
    ds[tid] = v;
    __syncthreads();
    #pragma unroll
    for (int d = 1; d < NDIGIT; d <<= 1) {
        int x = (tid >= d) ? ds[tid - d] : 0;
        __syncthreads();
        ds[tid] += x;
        __syncthreads();
    }
    const int incl = ds[tid];
    __syncthreads();
    ds[tid] = incl - v;     // exclusive
    if (tid < 128) { cnt128[tid] = 0; cur128[tid] = 0; }
    __syncthreads();

    const int s = ds[b];
    const int bucketsz = ((b + 1 < NDIGIT) ? ds[b + 1] : n_edges) - s;

    const int lane = tid & 63;
    const int wv = tid >> 6;           // 8 waves
    const int q  = lane >> 3;          // edge slot 0..7
    const int c8 = lane & 7;           // uint4 index within 128B row

    if (bucketsz <= LCAP) {
        for (int i = tid; i < bucketsz; i += 512) {
            const unsigned key = P1[s + i];
            stage[i] = key;
            atomicAdd(&cnt128[key >> 16], 1);
        }
        __syncthreads();
        if (tid < 64) {
            const int a = cnt128[2 * tid], bb = cnt128[2 * tid + 1];
            int p = a + bb;
            #pragma unroll
            for (int d = 1; d < 64; d <<= 1) {
                const int t = __shfl_up(p, d);
                if (tid >= d) p += t;
            }
            segbase[2 * tid]     = p - a - bb;
            segbase[2 * tid + 1] = p - bb;
            if (tid == 63) segbase[128] = p;
        }
        __syncthreads();
        for (int i = tid; i < bucketsz; i += 512) {
            const unsigned key = stage[i];
            const int nn = key >> 16;
            const int pos = atomicAdd(&cur128[nn], 1);
            lsrc[segbase[nn] + pos] = (unsigned short)key;
        }
        __syncthreads();
        for (int nn = wv; nn < 128; nn += 8) {
            const int node = n0 + nn;
            if (node >= n_nodes) break;
            const int ls = segbase[nn];
            const int le = segbase[nn + 1];
            float a0=0.f,a1=0.f,a2=0.f,a3=0.f,a4=0.f,a5=0.f,a6=0.f,a7=0.f;
            int e = ls + q;
            for (; e + 8 < le; e += 16) {
                const uint4 u = hwn4[(size_t)lsrc[e] * 8 + c8];
                const uint4 w2 = hwn4[(size_t)lsrc[e + 8] * 8 + c8];
                a0 += bflo(u.x) + bflo(w2.x); a1 += bfhi(u.x) + bfhi(w2.x);
                a2 += bflo(u.y) + bflo(w2.y); a3 += bfhi(u.y) + bfhi(w2.y);
                a4 += bflo(u.z) + bflo(w2.z); a5 += bfhi(u.z) + bfhi(w2.z);
                a6 += bflo(u.w) + bflo(w2.w); a7 += bfhi(u.w) + bfhi(w2.w);
            }
            for (; e < le; e += 8) {
                const uint4 u = hwn4[(size_t)lsrc[e] * 8 + c8];
                a0 += bflo(u.x); a1 += bfhi(u.x);
                a2 += bflo(u.y); a3 += bfhi(u.y);
                a4 += bflo(u.z); a5 += bfhi(u.z);
                a6 += bflo(u.w); a7 += bfhi(u.w);
            }
            #pragma unroll
            for (int d = 8; d < 64; d <<= 1) {
                a0 += __shfl_xor(a0, d); a1 += __shfl_xor(a1, d);
                a2 += __shfl_xor(a2, d); a3 += __shfl_xor(a3, d);
                a4 += __shfl_xor(a4, d); a5 += __shfl_xor(a5, d);
                a6 += __shfl_xor(a6, d); a7 += __shfl_xor(a7, d);
            }
            if (q == 0) {
                const float nv = norm[node];
                const float4 b0 = *reinterpret_cast<const float4*>(bias + c8 * 8);
                const float4 b1 = *reinterpret_cast<const float4*>(bias + c8 * 8 + 4);
                float4 o0, o1;
                o0.x = fmaxf(fmaf(a0, nv, b0.x), 0.f);
                o0.y = fmaxf(fmaf(a1, nv, b0.y), 0.f);
                o0.z = fmaxf(fmaf(a2, nv, b0.z), 0.f);
                o0.w = fmaxf(fmaf(a3, nv, b0.w), 0.f);
                o1.x = fmaxf(fmaf(a4, nv, b1.x), 0.f);
                o1.y = fmaxf(fmaf(a5, nv, b1.y), 0.f);
                o1.z = fmaxf(fmaf(a6, nv, b1.z), 0.f);
                o1.w = fmaxf(fmaf(a7, nv, b1.w), 0.f);
                float* po = out + (size_t)node * C_FEATS + c8 * 8;
                *reinterpret_cast<float4*>(po)     = o0;
                *reinterpret_cast<float4*>(po + 4) = o1;
            }
        }
    } else {
        // safe fallback for oversized buckets (never expected on this input)
        for (int nn = wv; nn < 128; nn += 8) {
            const int node = n0 + nn;
            if (node >= n_nodes) break;
            float a0=0.f,a1=0.f,a2=0.f,a3=0.f,a4=0.f,a5=0.f,a6=0.f,a7=0.f;
            for (int i = q; i < bucketsz; i += 8) {
                const unsigned key = P1[s + i];
                if ((int)(key >> 16) == nn) {
                    const uint4 u = hwn4[(size_t)(key & 0xFFFFu) * 8 + c8];
                    a0 += bflo(u.x); a1 += bfhi(u.x);
                    a2 += bflo(u.y); a3 += bfhi(u.y);
                    a4 += bflo(u.z); a5 += bfhi(u.z);
                    a6 += bflo(u.w); a7 += bfhi(u.w);
                }
            }
            #pragma unroll
            for (int d = 8; d < 64; d <<= 1) {
                a0 += __shfl_xor(a0, d); a1 += __shfl_xor(a1, d);
                a2 += __shfl_xor(a2, d); a3 += __shfl_xor(a3, d);
                a4 += __shfl_xor(a4, d); a5 += __shfl_xor(a5, d);
                a6 += __shfl_xor(a6, d); a7 += __shfl_xor(a7, d);
            }
            if (q == 0) {
                const float nv = norm[node];
                const float4 b0 = *reinterpret_cast<const float4*>(bias + c8 * 8);
                const float4 b1 = *reinterpret_cast<const float4*>(bias + c8 * 8 + 4);
                float4 o0, o1;
                o0.x = fmaxf(fmaf(a0, nv, b0.x), 0.f);
                o0.y = fmaxf(fmaf(a1, nv, b0.y), 0.f);
                o0.z = fmaxf(fmaf(a2, nv, b0.z), 0.f);
                o0.w = fmaxf(fmaf(a3, nv, b0.w), 0.f);
                o1.x = fmaxf(fmaf(a4, nv, b1.x), 0.f);
                o1.y = fmaxf(fmaf(a5, nv, b1.y), 0.f);
                o1.z = fmaxf(fmaf(a6, nv, b1.z), 0.f);
                o1.w = fmaxf(fmaf(a7, nv, b1.w), 0.f);
                float* po = out + (size_t)node * C_FEATS + c8 * 8;
                *reinterpret_cast<float4*>(po)     = o0;
                *reinterpret_cast<float4*>(po + 4) = o1;
            }
        }
    }
}

extern "C" void kernel_launch(void* const* d_in, const int* in_sizes, int n_in,
                              void* d_out, int out_size, void* d_ws, size_t ws_size,
                              hipStream_t stream) {
    const float* h      = (const float*)d_in[0];
    const float* norm   = (const float*)d_in[1];
    const int*   src    = (const int*)d_in[2];
    const int*   dst    = (const int*)d_in[3];
    const float* weight = (const float*)d_in[4];
    const float* bias   = (const float*)d_in[5];

    const int n_nodes = in_sizes[1];
    const int n_edges = in_sizes[2];

    char* ws = (char*)d_ws;
    unsigned* P1            = (unsigned*)(ws + 0);
    int* dm                 = (int*)(ws + 3200000);
    unsigned short* cm16    = (unsigned short*)(ws + 4801536);
    unsigned short* hwn     = (unsigned short*)(ws + 5602304);
    int* totals             = (int*)(ws + 12002304);
    unsigned short* wt_g    = (unsigned short*)(ws + 12004352);

    const int nchunk  = (n_edges + RCHUNK - 1) / RCHUNK;          // 782
    const int ngroup  = (n_nodes + 127) / 128;                    // 391
    const int nreb    = (nchunk + 3) / 4;                         // 196
    const int ngemm   = (n_nodes + 63) / 64;                      // 782

    // 1) fused digit histogram (u16 chunk-major) + W transpose
    packhist_w_kernel<<<nchunk + 16, 256, 0, stream>>>(dst, cm16, weight, wt_g,
                                                       n_edges, nchunk);
    // 2) per-bucket scan of chunk counts -> dm (within-bucket) + totals
    bucketscan_kernel<<<NDIGIT, 256, 0, stream>>>(cm16, dm, totals, nchunk);
    // 3) FUSED reorder (196 blocks) + gemm (782 blocks) — concurrent
    reorder_gemm_kernel<<<nreb + ngemm, 256, 0, stream>>>(
        src, dst, P1, dm, totals, h, wt_g, norm, hwn,
        n_edges, nchunk, n_nodes, nreb);
    // 4) bucket-local split + gather-aggregate + finalize
    aggregate_kernel<<<ngroup, 512, 0, stream>>>(
        (const uint4*)hwn, P1, totals, norm, bias, (float*)d_out, n_nodes, n_edges);
}